// Round 1
// 229.231 us; speedup vs baseline: 1.0522x; 1.0522x over previous
//
#include <hip/hip_runtime.h>

typedef unsigned short ushort_t;
typedef __attribute__((ext_vector_type(8))) __bf16 bf16x8;
typedef __attribute__((ext_vector_type(4))) float floatx4;

__device__ __forceinline__ ushort_t f2bf(float f) {
    unsigned int u = __builtin_bit_cast(unsigned int, f);
    u = (u + 0x7fffu + ((u >> 16) & 1u)) >> 16;
    return (ushort_t)u;
}

__device__ __forceinline__ void async16(const ushort_t* g, ushort_t* l) {
    __builtin_amdgcn_global_load_lds(
        (const __attribute__((address_space(1))) unsigned int*)g,
        (__attribute__((address_space(3))) unsigned int*)l,
        16 /*bytes*/, 0 /*offset*/, 0 /*aux*/);
}

// XOR-swizzled LDS offset (ushort index) of the 8-elem group (row, cg).
__device__ __forceinline__ int sw(int row, int cg) {
    return ((row << 2) + ((cg ^ row ^ (row >> 2)) & 3)) << 3;
}

// XCD-chunked bijective blockIdx swizzle (nwg % 8 == 0).
// HW assigns bid -> XCD (bid & 7); remap so each XCD owns a contiguous
// chunk of the logical grid (L2 panel sharing).  cpx = nwg / 8.
__device__ __forceinline__ int xcd_swz(int bid, int cpx) {
    return (bid & 7) * cpx + (bid >> 3);
}

template <int N>
__device__ __forceinline__ void vwait() {
    if constexpr (N == 0)      asm volatile("s_waitcnt vmcnt(0)" ::: "memory");
    else if constexpr (N == 3) asm volatile("s_waitcnt vmcnt(3)" ::: "memory");
    else if constexpr (N == 4) asm volatile("s_waitcnt vmcnt(4)" ::: "memory");
    else if constexpr (N == 6) asm volatile("s_waitcnt vmcnt(6)" ::: "memory");
    else if constexpr (N == 8) asm volatile("s_waitcnt vmcnt(8)" ::: "memory");
    else static_assert(N == 0, "unsupported vmcnt");
}

// ---------------------------------------------------------------------------
// NS-slot DMA-pipelined bf16 GEMM core (R9-verified K-loop order), templated
// on wave count and slot count. NW waves in (NW/2) x 2 grid, wave tile 64x64
// (IM=IN=4, mfma_16x16x32). BM = NW*32 rows, BN = 128.
// Per kstep k:  s_waitcnt vmcnt((NS-2)*Q)  (drain kstep k, keep k+1..k+NS-2)
//               s_barrier                  (all waves' k-loads now in LDS)
//               issue DMA for k+NS-1 into slot (k+NS-1)%NS (readers done)
//               ds_read slot k%NS ; MFMA
// NS=4 gives 3 ksteps (~960 cy) of latency coverage > ~900 cy HBM miss.
// ---------------------------------------------------------------------------
template <int BM, int BN, int IM, int IN, int NW, int NS>
__device__ __forceinline__ void gemm_core_p(
    const ushort_t* __restrict__ A, int lda,
    const ushort_t* __restrict__ B, int ldb,
    int K, int tile_m, int tile_n,
    ushort_t* buf,                    // NS * (BM+BN)*32 ushorts
    floatx4 (&acc)[IM][IN]) {

    constexpr int NT = NW * 64;
    constexpr int SA = BM * 4 / NT;       // 16B DMA instrs per kstep (A)
    constexpr int SB = BN * 4 / NT;
    constexpr int Q  = SA + SB;
    constexpr int SLOT = (BM + BN) * 32;  // ushorts per slot
    constexpr int BOFF = BM * 32;         // B region offset within slot

    const int tid  = threadIdx.x;
    const int lane = tid & 63;
    const int wave = tid >> 6;
    const int wm   = wave >> 1, wn = wave & 1;
    const int quad = lane >> 4;
    const int l16  = lane & 15;

#pragma unroll
    for (int i = 0; i < IM; i++)
#pragma unroll
        for (int j = 0; j < IN; j++) acc[i][j] = (floatx4){0.f, 0.f, 0.f, 0.f};

    const ushort_t* ga[SA];
    int la[SA];
#pragma unroll
    for (int s = 0; s < SA; s++) {
        int seg = tid + s * NT;
        int r = seg >> 2, c = (seg ^ r ^ (r >> 2)) & 3;
        ga[s] = A + (long)(r + tile_m) * lda + c * 8;
        la[s] = seg * 8;
    }
    const ushort_t* gb[SB];
    int lb[SB];
#pragma unroll
    for (int s = 0; s < SB; s++) {
        int seg = tid + s * NT;
        int r = seg >> 2, c = (seg ^ r ^ (r >> 2)) & 3;
        gb[s] = B + (long)(r + tile_n) * ldb + c * 8;
        lb[s] = BOFF + seg * 8;
    }

    const int nk = K >> 5;

    // prologue: issue ksteps 0..NS-2 into slots 0..NS-2
#pragma unroll
    for (int p = 0; p < NS - 1; ++p) {
#pragma unroll
        for (int s = 0; s < SA; s++) async16(ga[s] + p * 32, buf + p * SLOT + la[s]);
#pragma unroll
        for (int s = 0; s < SB; s++) async16(gb[s] + p * 32, buf + p * SLOT + lb[s]);
    }

    int slot = 0, slot2 = NS - 1;
    for (int k = 0; k < nk; ++k) {
        const int rem = nk - 1 - k;   // ksteps still in flight beyond k
        if (rem >= NS - 2) {
            vwait<(NS - 2) * Q>();
        } else if (NS >= 4 && rem == 1) {
            vwait<Q>();
        } else {
            vwait<0>();
        }
        __builtin_amdgcn_s_barrier();
        asm volatile("" ::: "memory");

        if (k + NS - 1 < nk) {
            const int koff = (k + NS - 1) << 5;
            ushort_t* dst = buf + slot2 * SLOT;
#pragma unroll
            for (int s = 0; s < SA; s++) async16(ga[s] + koff, dst + la[s]);
#pragma unroll
            for (int s = 0; s < SB; s++) async16(gb[s] + koff, dst + lb[s]);
        }

        const ushort_t* as = buf + slot * SLOT;
        const ushort_t* bs = as + BOFF;
        bf16x8 af[IM], bfr[IN];
#pragma unroll
        for (int im = 0; im < IM; im++)
            af[im] = *(const bf16x8*)&as[sw(wm * IM * 16 + im * 16 + l16, quad)];
#pragma unroll
        for (int in = 0; in < IN; in++)
            bfr[in] = *(const bf16x8*)&bs[sw(wn * IN * 16 + in * 16 + l16, quad)];
#pragma unroll
        for (int im = 0; im < IM; im++)
#pragma unroll
            for (int in = 0; in < IN; in++)
                acc[im][in] = __builtin_amdgcn_mfma_f32_16x16x32_bf16(
                    af[im], bfr[in], acc[im][in], 0, 0, 0);

        slot  = (slot == NS - 1) ? 0 : slot + 1;
        slot2 = (slot2 == NS - 1) ? 0 : slot2 + 1;
    }
}

// ---------------------------------------------------------------------------
// prep: fp32->bf16 for x & W_v, zero lsum, transpose+cast Wq/Wk -> WqT/WkT
// block ranges: [0,8192) x | [8192,9216) wv | [9216,9224) lsum | [9224,9736) T
// ---------------------------------------------------------------------------
__global__ void prep_kernel(const float* __restrict__ x,
                            const float* __restrict__ wq,
                            const float* __restrict__ wk,
                            const float* __restrict__ wv,
                            ushort_t* __restrict__ xb,
                            ushort_t* __restrict__ wvb,
                            ushort_t* __restrict__ wqT,
                            ushort_t* __restrict__ wkT,
                            float* __restrict__ lsum) {
    const int bx = blockIdx.x;
    const int t = threadIdx.x;
    if (bx < 9216) {
        const float* src;
        ushort_t* dst;
        long g;
        if (bx < 8192) { src = x;  dst = xb;  g = ((long)bx * 256 + t) * 4; }
        else           { src = wv; dst = wvb; g = ((long)(bx - 8192) * 256 + t) * 4; }
        float4 v = *(const float4*)(src + g);
        ushort4 o;
        o.x = f2bf(v.x); o.y = f2bf(v.y); o.z = f2bf(v.z); o.w = f2bf(v.w);
        *(ushort4*)(dst + g) = o;
        return;
    }
    if (bx < 9224) {
        int idx = (bx - 9216) * 256 + t;  // [0,2048)
        ((float4*)lsum)[idx] = (float4){0.f, 0.f, 0.f, 0.f};
        return;
    }
    // transpose tiles
    const int tt = bx - 9224;           // [0,512)
    const float* src = (tt >= 256) ? wk : wq;
    ushort_t* dst = (tt >= 256) ? wkT : wqT;
    const int id = tt & 255;
    const int h0 = (id >> 4) * 64, d0 = (id & 15) * 64;
    __shared__ ushort_t tile[64 * 80];
    {
        int i = t >> 2, cg = (t & 3) << 4;
        const float4* p = (const float4*)(src + (long)(h0 + i) * 1024 + d0 + cg);
#pragma unroll
        for (int k = 0; k < 4; k++) {
            float4 v = p[k];
            ushort_t* q = &tile[i * 80 + cg + k * 4];
            q[0] = f2bf(v.x); q[1] = f2bf(v.y); q[2] = f2bf(v.z); q[3] = f2bf(v.w);
        }
    }
    __syncthreads();
    {
        int j = t >> 2, ig = (t & 3) << 4;
        ushort_t tmp[16];
#pragma unroll
        for (int k = 0; k < 16; k++) tmp[k] = tile[(ig + k) * 80 + j];
        ushort_t* o = dst + (long)(d0 + j) * 1024 + h0 + ig;
        *(uint4*)o = ((uint4*)tmp)[0];
        *(uint4*)(o + 8) = ((uint4*)tmp)[1];
    }
}

// ---------------------------------------------------------------------------
// gv: blocks [0,32) -> G = contraction of WkT/WqT over h (256x128 tiles)
//     blocks [32,288) -> V^T = Wv x^T (256x128 tiles)
// 512 threads, 8 waves.  (not BW-bound: left unswizzled, NS=3)
// ---------------------------------------------------------------------------
__global__ __launch_bounds__(512, 4) void gv_kernel(
    const ushort_t* __restrict__ wkT, const ushort_t* __restrict__ wqT,
    const ushort_t* __restrict__ wvb, const ushort_t* __restrict__ xb,
    ushort_t* __restrict__ Gb, ushort_t* __restrict__ VTb) {

    __shared__ __align__(16) ushort_t buf[3 * 384 * 32];

    const ushort_t *A, *B;
    ushort_t* C;
    int ldc, tile_m, tile_n;
    if (blockIdx.x < 32) {   // G[e][d] = sum_h WkT[e][h] WqT[d][h]
        A = wkT; B = wqT; C = Gb; ldc = 1024;
        tile_m = (blockIdx.x >> 3) * 256;   // 4 m-tiles
        tile_n = (blockIdx.x & 7) * 128;    // 8 n-tiles
    } else {                 // VT[h][s] = sum_d Wv[h][d] x[s][d]
        int id = blockIdx.x - 32;           // [0,256)
        A = wvb; B = xb; C = VTb; ldc = 8192;
        tile_m = (id >> 6) * 256;           // 4 m-tiles
        tile_n = (id & 63) * 128;           // 64 n-tiles
    }

    floatx4 acc[4][4];
    gemm_core_p<256, 128, 4, 4, 8, 3>(A, 1024, B, 1024, 1024, tile_m, tile_n, buf, acc);

    const int lane = threadIdx.x & 63, wave = threadIdx.x >> 6;
    const int wm = wave >> 1, wn = wave & 1, quad = lane >> 4, l16 = lane & 15;
#pragma unroll
    for (int im = 0; im < 4; im++)
#pragma unroll
        for (int r = 0; r < 4; r++) {
            int row = tile_m + wm * 64 + im * 16 + quad * 4 + r;
#pragma unroll
            for (int in = 0; in < 4; in++) {
                int col = tile_n + wn * 64 + in * 16 + l16;
                C[(long)row * ldc + col] = f2bf(acc[im][in][r]);
            }
        }
}

// ---------------------------------------------------------------------------
// Y = x G^T  (M=8192, N=1024, K=1024; 128x128 tiles, 512 blocks = 2/CU)
// NS=4 quad-buffer (3 ksteps in flight) + XCD-chunked swizzle.
// ---------------------------------------------------------------------------
__global__ __launch_bounds__(256) void y_kernel(
    const ushort_t* __restrict__ xb,
    const ushort_t* __restrict__ Gb,
    ushort_t* __restrict__ Yb) {

    __shared__ __align__(16) ushort_t buf[4 * 256 * 32];
    const int lin = xcd_swz(blockIdx.x, 64);   // 512 blocks
    const int tile_n = (lin & 7) * 128;        // 8 n-tiles (fastest)
    const int tile_m = (lin >> 3) * 128;       // 64 m-tiles

    floatx4 acc[4][4];
    gemm_core_p<128, 128, 4, 4, 4, 4>(xb, 1024, Gb, 1024, 1024, tile_m, tile_n, buf, acc);

    const int lane = threadIdx.x & 63, wave = threadIdx.x >> 6;
    const int wm = wave >> 1, wn = wave & 1, quad = lane >> 4, l16 = lane & 15;
#pragma unroll
    for (int im = 0; im < 4; im++)
#pragma unroll
        for (int r = 0; r < 4; r++) {
            int row = tile_m + wm * 64 + im * 16 + quad * 4 + r;
#pragma unroll
            for (int in = 0; in < 4; in++) {
                int col = tile_n + wn * 64 + in * 16 + l16;
                Yb[(long)row * 1024 + col] = f2bf(acc[im][in][r]);
            }
        }
}

// ---------------------------------------------------------------------------
// P = exp(scale * Y x^T) per batch + fused row-sum atomics.
// 256x128 tiles, 512 thr, 72KB LDS -> exactly 2 blocks/CU; grid 512 = 2/CU.
// XCD-chunked swizzle for Y-panel / x-tile L2 sharing.
// ---------------------------------------------------------------------------
__global__ __launch_bounds__(512, 4) void pexp_kernel(
    const ushort_t* __restrict__ Yb,
    const ushort_t* __restrict__ xb,
    ushort_t* __restrict__ Pb,
    float* __restrict__ lsum) {

    __shared__ __align__(16) ushort_t buf[3 * 384 * 32];

    const int lin = xcd_swz(blockIdx.x, 64);   // 512 blocks
    const int z = lin >> 7;                    // batch
    const int tile_m = ((lin >> 4) & 7) * 256; // 8 m-tiles
    const int tile_n = (lin & 15) * 128;       // 16 n-tiles (fastest)

    const ushort_t* A = Yb + (long)z * 2097152;
    const ushort_t* B = xb + (long)z * 2097152;
    ushort_t* C = Pb + (long)z * 4194304;
    float* l = lsum + z * 2048;

    floatx4 acc[4][4];
    gemm_core_p<256, 128, 4, 4, 8, 3>(A, 1024, B, 1024, 1024, tile_m, tile_n, buf, acc);

    const float scale = 0.022097086912079608f;  // 1/sqrt(2048)
    const int lane = threadIdx.x & 63, wave = threadIdx.x >> 6;
    const int wm = wave >> 1, wn = wave & 1, quad = lane >> 4, l16 = lane & 15;
#pragma unroll
    for (int im = 0; im < 4; im++)
#pragma unroll
        for (int r = 0; r < 4; r++) {
            int row = tile_m + wm * 64 + im * 16 + quad * 4 + r;
            float psum = 0.f;
#pragma unroll
            for (int in = 0; in < 4; in++) {
                int col = tile_n + wn * 64 + in * 16 + l16;
                float e = __expf(acc[im][in][r] * scale);
                C[(long)row * 2048 + col] = f2bf(e);
                psum += e;
            }
            psum += __shfl_xor(psum, 1, 64);
            psum += __shfl_xor(psum, 2, 64);
            psum += __shfl_xor(psum, 4, 64);
            psum += __shfl_xor(psum, 8, 64);
            if (l16 == 0) atomicAdd(&l[row], psum);
        }
}

// ---------------------------------------------------------------------------
// out = (P V) / l per batch  (128x128 tiles, 512 blocks = 2/CU)
// NS=4 quad-buffer (covers ~900cy HBM latency) + XCD-chunked swizzle.
// ---------------------------------------------------------------------------
__global__ __launch_bounds__(256) void out_kernel(
    const ushort_t* __restrict__ Pb,
    const ushort_t* __restrict__ VTb,
    float* __restrict__ out,
    const float* __restrict__ lsum) {

    __shared__ __align__(16) ushort_t buf[4 * 256 * 32];

    const int lin = xcd_swz(blockIdx.x, 64);   // 512 blocks
    const int z = lin >> 7;                    // batch
    const int tile_m = ((lin >> 3) & 15) * 128;// 16 m-tiles
    const int tile_n = (lin & 7) * 128;        // 8 n-tiles (fastest)

    const ushort_t* A = Pb + (long)z * 4194304;   // [2048][2048]
    const ushort_t* B = VTb + (long)z * 2048;     // ldb=8192, batch col slice
    float* C = out + (long)z * 2097152;
    const float* l = lsum + z * 2048;

    floatx4 acc[4][4];
    gemm_core_p<128, 128, 4, 4, 4, 4>(A, 2048, B, 8192, 2048, tile_m, tile_n, buf, acc);

    const int lane = threadIdx.x & 63, wave = threadIdx.x >> 6;
    const int wm = wave >> 1, wn = wave & 1, quad = lane >> 4, l16 = lane & 15;
#pragma unroll
    for (int im = 0; im < 4; im++)
#pragma unroll
        for (int r = 0; r < 4; r++) {
            int row = tile_m + wm * 64 + im * 16 + quad * 4 + r;
            float li = 1.0f / l[row];
#pragma unroll
            for (int in = 0; in < 4; in++) {
                int col = tile_n + wn * 64 + in * 16 + l16;
                C[(long)row * 1024 + col] = acc[im][in][r] * li;
            }
        }
}

// ---------------------------------------------------------------------------
extern "C" void kernel_launch(void* const* d_in, const int* in_sizes, int n_in,
                              void* d_out, int out_size, void* d_ws, size_t ws_size,
                              hipStream_t stream) {
    const float* x  = (const float*)d_in[0];
    const float* wq = (const float*)d_in[1];
    const float* wk = (const float*)d_in[2];
    const float* wv = (const float*)d_in[3];

    ushort_t* xb  = (ushort_t*)d_ws;          // [8192,1024] bf16
    ushort_t* wvb = xb  + 8388608;            // [1024,1024]
    ushort_t* wqT = wvb + 1048576;            // [1024,1024]  Wq^T bf16
    ushort_t* wkT = wqT + 1048576;            // [1024,1024]  Wk^T bf16
    ushort_t* Gb  = wkT + 1048576;            // [1024,1024]  G[e][d]
    ushort_t* Yb  = Gb  + 1048576;            // [8192,1024]  Y = x G^T
    ushort_t* VTb = Yb  + 8388608;            // [1024,8192]
    ushort_t* Pb  = VTb + 8388608;            // [4][2048][2048]
    float*    lsum = (float*)(Pb + 16777216); // [4][2048] fp32 row sums
    float*    out  = (float*)d_out;

    // 1) cvt x/wv + zero lsum + transpose wq/wk
    prep_kernel<<<9736, 256, 0, stream>>>(x, wq, wk, wv, xb, wvb, wqT, wkT, lsum);

    // 2) G (32 blocks) + V^T (256 blocks), 512 thr
    gv_kernel<<<288, 512, 0, stream>>>(wkT, wqT, wvb, xb, Gb, VTb);

    // 3) Y = x G^T (512 blocks = 2/CU, NS=4, XCD swizzle)
    y_kernel<<<512, 256, 0, stream>>>(xb, Gb, Yb);

    // 4) P = exp(scale * Y x^T) + row sums (512 blocks = 2/CU, XCD swizzle)
    pexp_kernel<<<512, 512, 0, stream>>>(Yb, xb, Pb, lsum);

    // 5) out = (P V) / l (512 blocks = 2/CU, NS=4, XCD swizzle)
    out_kernel<<<512, 256, 0, stream>>>(Pb, VTb, out, lsum);
}